// Round 14
// baseline (174.955 us; speedup 1.0000x reference)
//
#include <hip/hip_runtime.h>
#include <math.h>

#define M_NODES 20000
#define MPAD    20096
#define NE      320000
#define NC      4
#define NH      4
#define DIN     256
#define DOUT    128
#define DCAT    512

// CSR bucket-build parameters (64-row buckets)
#define RPB2  64
#define NBKT2 313     // ceil(20000/64)
#define EPB   2048
#define NBLK  157
#define CAP2  4096

typedef __attribute__((ext_vector_type(8))) _Float16 half8v;
typedef __attribute__((ext_vector_type(2))) _Float16 half2v;
typedef __attribute__((ext_vector_type(4))) float f32x4;

__device__ __forceinline__ unsigned short f2h(float x) {
    _Float16 h = (_Float16)x;
    return __builtin_bit_cast(unsigned short, h);
}
__device__ __forceinline__ void gload16(const void* g, void* l) {
    __builtin_amdgcn_global_load_lds(
        (const __attribute__((address_space(1))) void*)g,
        (__attribute__((address_space(3))) void*)l,
        16, 0, 0);
}

// ---------------- fused prep: cvtA (u,i) | bcount | prepB | Bvec ----------------
// grid.x: [0,2500) cvtA-u, [2500,5000) cvtA-i, [5000,6256) bcount, [6256,6384) prepB, [6384,6392) Bvec
__global__ __launch_bounds__(256) void k_prep(const float* __restrict__ u_prev, const float* __restrict__ i_prev,
                                              const float* __restrict__ w_user, const float* __restrict__ w_item,
                                              const float* __restrict__ a_u_src, const float* __restrict__ a_u_dst,
                                              const float* __restrict__ a_i_src, const float* __restrict__ a_i_dst,
                                              const int* __restrict__ u2i_row, const int* __restrict__ i2u_row,
                                              unsigned short* __restrict__ AbU, unsigned short* __restrict__ AbI,
                                              unsigned short* __restrict__ BTu, unsigned short* __restrict__ BTi,
                                              unsigned short* __restrict__ Bvec, int* __restrict__ cnt3) {
    __shared__ int hist[NBKT2];
    int bid = blockIdx.x, tid = threadIdx.x;
    if (bid < 5000) {
        int sideI = bid >= 2500;
        int t = (sideI ? bid - 2500 : bid) * 256 + tid;
        int row = t >> 5, kc = (t & 31) * 8;
        const float* src = sideI ? i_prev : u_prev;
        unsigned short* dst = sideI ? AbI : AbU;
        float4 x0 = *(const float4*)(src + (size_t)row * DIN + kc);
        float4 x1 = *(const float4*)(src + (size_t)row * DIN + kc + 4);
        float xs[8] = {x0.x, x0.y, x0.z, x0.w, x1.x, x1.y, x1.z, x1.w};
        unsigned int H[4];
#pragma unroll
        for (int p = 0; p < 4; ++p)
            H[p] = (unsigned int)f2h(xs[2 * p]) | ((unsigned int)f2h(xs[2 * p + 1]) << 16);
        *(uint4*)(dst + (size_t)row * 256 + kc) = make_uint4(H[0], H[1], H[2], H[3]);
        return;
    }
    if (bid < 6256) {
        // ---- bcount (int4-vectorized, 64-row buckets) ----
        int sub = bid - 5000;
        int combo = sub / NBLK, blk = sub % NBLK;
        int c = combo >> 1, dir = combo & 1;
        const int* rows = (dir ? i2u_row : u2i_row) + (size_t)c * NE;
        for (int i = tid; i < NBKT2; i += 256) hist[i] = 0;
        __syncthreads();
        int e0 = blk * EPB + tid * 8;
        if (e0 + 8 <= NE) {
            int4 r0 = *(const int4*)(rows + e0);
            int4 r1 = *(const int4*)(rows + e0 + 4);
            atomicAdd(&hist[r0.x >> 6], 1); atomicAdd(&hist[r0.y >> 6], 1);
            atomicAdd(&hist[r0.z >> 6], 1); atomicAdd(&hist[r0.w >> 6], 1);
            atomicAdd(&hist[r1.x >> 6], 1); atomicAdd(&hist[r1.y >> 6], 1);
            atomicAdd(&hist[r1.z >> 6], 1); atomicAdd(&hist[r1.w >> 6], 1);
        }
        __syncthreads();
        for (int i = tid; i < NBKT2; i += 256)
            cnt3[((size_t)combo * NBKT2 + i) * NBLK + blk] = hist[i];
        return;
    }
    if (bid < 6384) {
        // ---- prepB: cumsum + transpose -> BT [512(n)][256(k)] fp16 ----
        int idx = (bid - 6256) * 256 + tid;
        int k = idx >> 7, j = idx & 127;
        float su = 0.f, si = 0.f;
        for (int c = 0; c < NC; ++c) {
            su += w_user[((size_t)c * DIN + k) * DOUT + j];
            si += w_item[((size_t)c * DIN + k) * DOUT + j];
            size_t n = (size_t)(c * DOUT + j) * 256;
            BTu[n + k] = f2h(su);
            BTi[n + k] = f2h(si);
        }
        return;
    }
    {
        // ---- Bvec: per-(side,c) fragment-major attention matrix ----
        int t = (bid - 6384) * 256 + tid;
        int lane = t & 63, ks = (t >> 6) & 3, c = (t >> 8) & 3, side = t >> 10;
        int col = lane & 15, g = lane >> 4;
        int kind = (col >> 2) & 1, h = col & 3;
        const float* araw = kind ? (side ? a_u_dst : a_i_dst) : (side ? a_i_src : a_u_src);
        unsigned int out2[4];
#pragma unroll
        for (int p = 0; p < 4; ++p) {
            unsigned short e2[2];
#pragma unroll
            for (int q = 0; q < 2; ++q) {
                int j = p * 2 + q;
                int kdim = ks * 32 + g * 8 + j;
                float s = 0.f;
                if (col < 8)
                    for (int c2 = 0; c2 <= c; ++c2) s += araw[(h * NC + c2) * DOUT + kdim];
                e2[q] = f2h(s);
            }
            out2[p] = (unsigned int)e2[0] | ((unsigned int)e2[1] << 16);
        }
        *(uint4*)(Bvec + ((size_t)(((side * 4 + c) * 4 + ks) * 64 + lane)) * 8) =
            make_uint4(out2[0], out2[1], out2[2], out2[3]);
    }
}

// ---------------- fused: MFMA GEMM K=256 fp16 + score epilogue (1256) | scan2 (8) ----------------
__global__ __launch_bounds__(256) void k_gmm(const unsigned short* __restrict__ AbU,
                                             const unsigned short* __restrict__ AbI,
                                             const unsigned short* __restrict__ BTu,
                                             const unsigned short* __restrict__ BTi,
                                             const unsigned short* __restrict__ Bvec,
                                             unsigned short* __restrict__ fbu,
                                             unsigned short* __restrict__ fbi,
                                             float* __restrict__ su_src, float* __restrict__ su_dst,
                                             float* __restrict__ si_src, float* __restrict__ si_dst,
                                             int* __restrict__ cnt3, int* __restrict__ btot,
                                             int* __restrict__ bbase) {
    __shared__ unsigned short As[128 * 64];
    __shared__ unsigned short Bs[128 * 64];
    __shared__ int tot[NBKT2];
    int bid = blockIdx.x, tid = threadIdx.x;
    if (bid < 1256) {
        int side = bid >= 628;
        int t = side ? bid - 628 : bid;
        int c = t / 157, mb = t % 157;
        const unsigned short* Ab = side ? AbI : AbU;
        const unsigned short* BT = side ? BTi : BTu;
        unsigned short* fb       = side ? fbi : fbu;
        int m0 = mb * 128;
        int w = tid >> 6, lane = tid & 63;
        int wrb = (w >> 1) * 64, wcb = (w & 1) * 64;
        int l15 = lane & 15, g = lane >> 4;
        int srow = lane >> 3, scol = (lane & 7) * 8;
        f32x4 acc[4][4] = {};
        for (int kt = 0; kt < 4; ++kt) {
            int k0 = kt * 64;
#pragma unroll
            for (int tt = 0; tt < 4; ++tt) {
                int chunk = w * 4 + tt;
                int row8 = chunk * 8 + srow;
                gload16(Ab + (size_t)(m0 + row8) * 256 + k0 + scol, (char*)As + chunk * 1024);
                gload16(BT + (size_t)(c * 128 + row8) * 256 + k0 + scol, (char*)Bs + chunk * 1024);
            }
            __syncthreads();
#pragma unroll
            for (int ks = 0; ks < 2; ++ks) {
                half8v a[4], b[4];
#pragma unroll
                for (int i = 0; i < 4; ++i)
                    a[i] = *(const half8v*)(&As[(wrb + i * 16 + l15) * 64 + ks * 32 + g * 8]);
#pragma unroll
                for (int j = 0; j < 4; ++j)
                    b[j] = *(const half8v*)(&Bs[(wcb + j * 16 + l15) * 64 + ks * 32 + g * 8]);
#pragma unroll
                for (int i = 0; i < 4; ++i)
#pragma unroll
                    for (int j = 0; j < 4; ++j)
                        acc[i][j] = __builtin_amdgcn_mfma_f32_16x16x32_f16(a[i], b[j], acc[i][j], 0, 0, 0);
            }
            __syncthreads();
        }
        // epilogue: write fb to global AND to LDS fp16 tile
#pragma unroll
        for (int i = 0; i < 4; ++i) {
#pragma unroll
            for (int r = 0; r < 4; ++r) {
                int nl = wrb + i * 16 + g * 4 + r;
                int node = m0 + nl;
                bool valid = node < M_NODES;
#pragma unroll
                for (int j = 0; j < 4; ++j) {
                    int d = wcb + j * 16 + l15;
                    unsigned short hv = f2h(acc[i][j][r]);
                    if (valid) fb[((size_t)c * M_NODES + node) * DOUT + d] = hv;
                    if (d < 64) As[nl * 64 + d] = hv;
                    else        Bs[nl * 64 + (d - 64)] = hv;
                }
            }
        }
        __syncthreads();
        // scores
        {
            half8v bv[4];
#pragma unroll
            for (int ks = 0; ks < 4; ++ks)
                bv[ks] = *(const half8v*)(Bvec + ((size_t)(((side * 4 + c) * 4 + ks) * 64 + lane)) * 8);
#pragma unroll
            for (int mt2 = 0; mt2 < 2; ++mt2) {
                int mt = w * 2 + mt2;
                f32x4 sacc = {};
#pragma unroll
                for (int ks = 0; ks < 4; ++ks) {
                    int nl = mt * 16 + l15;
                    const unsigned short* base = (ks < 2) ? As : Bs;
                    half8v a = *(const half8v*)(&base[nl * 64 + (ks & 1) * 32 + g * 8]);
                    sacc = __builtin_amdgcn_mfma_f32_16x16x32_f16(a, bv[ks], sacc, 0, 0, 0);
                }
                int col = l15;
                if (col < 8) {
                    int kind = col >> 2, h = col & 3;
                    float* dst = kind ? (side ? si_dst : su_dst) : (side ? si_src : su_src);
#pragma unroll
                    for (int r = 0; r < 4; ++r) {
                        int node = m0 + mt * 16 + g * 4 + r;
                        if (node < M_NODES)
                            dst[((size_t)c * M_NODES + node) * 4 + h] = sacc[r];
                    }
                }
            }
        }
        return;
    }
    {
        // ---- scan2 over 313 buckets ----
        int combo = bid - 1256;
        for (int bkt = tid; bkt < NBKT2; bkt += 256) {
            size_t basep = ((size_t)combo * NBKT2 + bkt) * NBLK;
            int run = 0;
            for (int b = 0; b < NBLK; ++b) {
                int v = cnt3[basep + b];
                cnt3[basep + b] = run;
                run += v;
            }
            tot[bkt] = run;
            btot[combo * NBKT2 + bkt] = run;
        }
        __syncthreads();
        if (tid < 64) {
            int carry = 0;
            for (int ch = 0; ch < 5; ++ch) {
                int idx = ch * 64 + tid;
                int v = (idx < NBKT2) ? tot[idx] : 0;
                int inc = v;
                for (int o = 1; o < 64; o <<= 1) {
                    int tv = __shfl_up(inc, o);
                    if (tid >= o) inc += tv;
                }
                if (idx < NBKT2) bbase[combo * NBKT2 + idx] = carry + inc - v;
                carry += __shfl(inc, 63);
            }
        }
    }
}

// ---------------- bfill (int4-vectorized), 1-D grid 1256 ----------------
__global__ __launch_bounds__(256) void k_bfill(const int* __restrict__ u2i_row, const int* __restrict__ u2i_col,
                                               const int* __restrict__ i2u_row, const int* __restrict__ i2u_col,
                                               const int* __restrict__ cnt3, const int* __restrict__ bbase,
                                               unsigned int* __restrict__ pairbuf) {
    __shared__ int cur[NBKT2];
    int bid = blockIdx.x, tid = threadIdx.x;
    int combo = bid / NBLK, blk = bid % NBLK;
    int c = combo >> 1, dir = combo & 1;
    const int* rows = (dir ? i2u_row : u2i_row) + (size_t)c * NE;
    const int* cols = (dir ? i2u_col : u2i_col) + (size_t)c * NE;
    for (int i = tid; i < NBKT2; i += 256)
        cur[i] = bbase[combo * NBKT2 + i] + cnt3[((size_t)combo * NBKT2 + i) * NBLK + blk];
    __syncthreads();
    unsigned int* pb = pairbuf + (size_t)combo * NE;
    int e0 = blk * EPB + tid * 8;
    if (e0 + 8 <= NE) {
        int4 r0 = *(const int4*)(rows + e0);
        int4 r1 = *(const int4*)(rows + e0 + 4);
        int4 c0 = *(const int4*)(cols + e0);
        int4 c1 = *(const int4*)(cols + e0 + 4);
        int rr[8] = {r0.x, r0.y, r0.z, r0.w, r1.x, r1.y, r1.z, r1.w};
        int cc[8] = {c0.x, c0.y, c0.z, c0.w, c1.x, c1.y, c1.z, c1.w};
#pragma unroll
        for (int k = 0; k < 8; ++k) {
            int pos = atomicAdd(&cur[rr[k] >> 6], 1);
            pb[pos] = ((unsigned int)rr[k] << 16) | (unsigned int)cc[k];
        }
    }
}

// ---------------- full-wave fallback for one row (cols from LDS) ----------------
__device__ void attend_row_wave(int r, int s0, int deg, const float* __restrict__ ssrc,
                                const float* __restrict__ sdst, const unsigned short* __restrict__ fbd,
                                const int* co, float* __restrict__ o, int lane) {
    if (deg <= 64) {
        float w = 0.f;
        int cl = 0;
        if (deg > 0) {
            float4 ssv = *(const float4*)(ssrc + (size_t)r * 4);
            float ss[4] = {ssv.x, ssv.y, ssv.z, ssv.w};
            float lg[4];
            if (lane < deg) {
                cl = co[s0 + lane];
                float4 sdv = *(const float4*)(sdst + (size_t)cl * 4);
                float sd[4] = {sdv.x, sdv.y, sdv.z, sdv.w};
#pragma unroll
                for (int h = 0; h < 4; ++h) {
                    float x = ss[h] + sd[h];
                    lg[h] = x > 0.f ? x : 0.01f * x;
                }
            } else {
#pragma unroll
                for (int h = 0; h < 4; ++h) lg[h] = -1e30f;
            }
            float ex[4], den[4];
#pragma unroll
            for (int h = 0; h < 4; ++h) {
                ex[h] = __expf(fminf(lg[h], 80.f));
                den[h] = ex[h];
            }
#pragma unroll
            for (int h = 0; h < 4; ++h)
                for (int o2 = 32; o2; o2 >>= 1) den[h] += __shfl_xor(den[h], o2);
#pragma unroll
            for (int h = 0; h < 4; ++h) w += ex[h] * (1.f / den[h]);
        }
        int q = lane >> 4, l16 = lane & 15;
        const unsigned short* fbl = fbd + l16 * 8;
        float a8[8] = {};
        for (int j = 0; j < deg; j += 4) {
            int e = j + q;
            float we = __shfl(w, e & 63);
            int   ce = __shfl(cl, e & 63);
            if (e < deg) {
                half8v v = *(const half8v*)(fbl + (size_t)ce * DOUT);
#pragma unroll
                for (int k = 0; k < 8; ++k) a8[k] = fmaf(we, (float)v[k], a8[k]);
            }
        }
#pragma unroll
        for (int i = 0; i < 8; ++i) {
            a8[i] += __shfl_xor(a8[i], 16);
            a8[i] += __shfl_xor(a8[i], 32);
        }
        if (lane < 16) {
            float4 r0 = make_float4(fmaxf(a8[0], 0.f), fmaxf(a8[1], 0.f), fmaxf(a8[2], 0.f), fmaxf(a8[3], 0.f));
            float4 r1 = make_float4(fmaxf(a8[4], 0.f), fmaxf(a8[5], 0.f), fmaxf(a8[6], 0.f), fmaxf(a8[7], 0.f));
            *(float4*)(o + l16 * 8) = r0;
            *(float4*)(o + l16 * 8 + 4) = r1;
        }
        return;
    }
    // slow path (deg > 64)
    float acc0 = 0.f, acc1 = 0.f;
    {
        float4 ssv = *(const float4*)(ssrc + (size_t)r * 4);
        float ss[4] = {ssv.x, ssv.y, ssv.z, ssv.w};
        float den[4] = {0.f, 0.f, 0.f, 0.f};
        for (int base = 0; base < deg; base += 64) {
            int e = base + lane;
            float ex[4] = {0.f, 0.f, 0.f, 0.f};
            if (e < deg) {
                int cl = co[s0 + e];
                float4 sdv = *(const float4*)(sdst + (size_t)cl * 4);
                float sd[4] = {sdv.x, sdv.y, sdv.z, sdv.w};
#pragma unroll
                for (int h = 0; h < 4; ++h) {
                    float x = ss[h] + sd[h];
                    x = x > 0.f ? x : 0.01f * x;
                    ex[h] = __expf(fminf(x, 80.f));
                }
            }
#pragma unroll
            for (int h = 0; h < 4; ++h) {
                float v = ex[h];
                for (int o2 = 32; o2; o2 >>= 1) v += __shfl_xor(v, o2);
                den[h] += v;
            }
        }
        float inv[4];
#pragma unroll
        for (int h = 0; h < 4; ++h) inv[h] = 1.f / den[h];
        for (int base = 0; base < deg; base += 64) {
            int e = base + lane;
            float w = 0.f;
            int cl = 0;
            if (e < deg) {
                cl = co[s0 + e];
                float4 sdv = *(const float4*)(sdst + (size_t)cl * 4);
                float sd[4] = {sdv.x, sdv.y, sdv.z, sdv.w};
#pragma unroll
                for (int h = 0; h < 4; ++h) {
                    float x = ss[h] + sd[h];
                    x = x > 0.f ? x : 0.01f * x;
                    w += __expf(fminf(x, 80.f)) * inv[h];
                }
            }
            int cnt2 = min(64, deg - base);
            for (int j = 0; j < cnt2; ++j) {
                float wj = __shfl(w, j);
                int   cj = __shfl(cl, j);
                half2v hv = *(const half2v*)(fbd + (size_t)cj * DOUT + lane * 2);
                acc0 = fmaf(wj, (float)hv[0], acc0);
                acc1 = fmaf(wj, (float)hv[1], acc1);
            }
        }
    }
    o[lane * 2]     = fmaxf(acc0, 0.f);
    o[lane * 2 + 1] = fmaxf(acc1, 0.f);
}

// ---------------- fused finalize+attend: 64-row buckets, grid 313*8 ----------------
__global__ __launch_bounds__(256) void k_fat(const unsigned int* __restrict__ pairbuf,
                                             const int* __restrict__ bbase, const int* __restrict__ btot,
                                             const unsigned short* __restrict__ fbu,
                                             const unsigned short* __restrict__ fbi,
                                             const float* __restrict__ su_src, const float* __restrict__ su_dst,
                                             const float* __restrict__ si_src, const float* __restrict__ si_dst,
                                             float* __restrict__ out) {
    __shared__ int hist[RPB2];    // inclusive per-row counts after scan
    __shared__ int cur[RPB2];
    __shared__ int lcol[CAP2];
    int tid = threadIdx.x, bid = blockIdx.x;
    int combo = bid & 7, bkt = bid >> 3;
    int c = combo >> 1, dir = combo & 1;
    int base = bbase[combo * NBKT2 + bkt];
    int cntb = btot[combo * NBKT2 + bkt];
    const unsigned int* pb = pairbuf + (size_t)combo * NE + base;
    // phase 1: bucket CSR in LDS
    if (tid < RPB2) hist[tid] = 0;
    __syncthreads();
    for (int k = tid; k < cntb; k += 256)
        atomicAdd(&hist[(pb[k] >> 16) & (RPB2 - 1)], 1);
    __syncthreads();
    if (tid < 64) {               // single-wave inclusive scan over 64 rows
        int v = hist[tid];
        int inc = v;
        for (int o = 1; o < 64; o <<= 1) {
            int t = __shfl_up(inc, o);
            if (tid >= o) inc += t;
        }
        hist[tid] = inc;
        cur[tid] = inc - v;
    }
    __syncthreads();
    for (int k = tid; k < cntb; k += 256) {
        unsigned int p = pb[k];
        int rl  = (p >> 16) & (RPB2 - 1);
        int pos = atomicAdd(&cur[rl], 1);
        if (pos < CAP2) lcol[pos] = (int)(p & 0xffffu);
    }
    __syncthreads();
    // phase 2: attend 64 rows (8 iters x 8 rows: 4 waves x 2 half-rows)
    const float* ssrc = (dir ? si_src : su_src) + (size_t)c * M_NODES * NH;
    const float* sdst = (dir ? su_dst : si_dst) + (size_t)c * M_NODES * NH;
    const unsigned short* fbd = (dir ? fbu : fbi) + (size_t)c * M_NODES * DOUT;
    int wavein = tid >> 6, lane = tid & 63;
    int half = lane >> 5, l = lane & 31;
    for (int iter = 0; iter < 8; ++iter) {
        int rloc = iter * 8 + wavein * 2 + half;
        int r = bkt * RPB2 + rloc;
        int start = rloc ? hist[rloc - 1] : 0;
        int deg = hist[rloc] - start;
        int degmax = max(deg, __shfl_xor(deg, 32));
        bool valid = r < M_NODES;
        float* o = out + ((size_t)(dir ? M_NODES + r : r)) * DCAT + c * DOUT;
        if (degmax <= 32) {
            unsigned int pk = 0;
            if (deg > 0) {
                float w = 0.f;
                int cl = 0;
                float4 ssv = *(const float4*)(ssrc + (size_t)r * 4);
                float ss[4] = {ssv.x, ssv.y, ssv.z, ssv.w};
                float lg[4];
                if (l < deg) {
                    cl = lcol[start + l];
                    float4 sdv = *(const float4*)(sdst + (size_t)cl * 4);
                    float sd[4] = {sdv.x, sdv.y, sdv.z, sdv.w};
#pragma unroll
                    for (int h = 0; h < 4; ++h) {
                        float x = ss[h] + sd[h];
                        lg[h] = x > 0.f ? x : 0.01f * x;
                    }
                } else {
#pragma unroll
                    for (int h = 0; h < 4; ++h) lg[h] = -1e30f;
                }
                float ex[4], den[4];
#pragma unroll
                for (int h = 0; h < 4; ++h) {
                    ex[h] = __expf(fminf(lg[h], 80.f));
                    den[h] = ex[h];
                }
#pragma unroll
                for (int h = 0; h < 4; ++h)
                    for (int o2 = 16; o2; o2 >>= 1) den[h] += __shfl_xor(den[h], o2);
#pragma unroll
                for (int h = 0; h < 4; ++h) w += ex[h] * (1.f / den[h]);
                pk = ((unsigned int)f2h(w) << 16) | (unsigned int)(cl & 0xffff);
            }
            int q2 = (l >> 4), l16 = l & 15;
            const char* fc = (const char*)(fbd + l16 * 8);
            half8v ah = {};
            int hb = half * 32;
            int j = 0;
            for (; j + 8 <= deg; j += 8) {
                unsigned int p0 = __shfl(pk, hb + j + q2);
                unsigned int p1 = __shfl(pk, hb + j + 2 + q2);
                unsigned int p2 = __shfl(pk, hb + j + 4 + q2);
                unsigned int p3 = __shfl(pk, hb + j + 6 + q2);
                half8v v0 = *(const half8v*)(fc + ((size_t)(p0 & 0xffffu) << 8));
                half8v v1 = *(const half8v*)(fc + ((size_t)(p1 & 0xffffu) << 8));
                half8v v2 = *(const half8v*)(fc + ((size_t)(p2 & 0xffffu) << 8));
                half8v v3 = *(const half8v*)(fc + ((size_t)(p3 & 0xffffu) << 8));
                ah += v0 * __builtin_bit_cast(_Float16, (unsigned short)(p0 >> 16));
                ah += v1 * __builtin_bit_cast(_Float16, (unsigned short)(p1 >> 16));
                ah += v2 * __builtin_bit_cast(_Float16, (unsigned short)(p2 >> 16));
                ah += v3 * __builtin_bit_cast(_Float16, (unsigned short)(p3 >> 16));
            }
            for (; j < deg; j += 4) {
                int e0 = j + q2, e1 = j + 2 + q2;
                unsigned int p0 = __shfl(pk, hb + min(e0, 31));
                unsigned int p1 = __shfl(pk, hb + min(e1, 31));
                p0 = (e0 < deg) ? p0 : 0u;
                p1 = (e1 < deg) ? p1 : 0u;
                half8v v0 = *(const half8v*)(fc + ((size_t)(p0 & 0xffffu) << 8));
                half8v v1 = *(const half8v*)(fc + ((size_t)(p1 & 0xffffu) << 8));
                ah += v0 * __builtin_bit_cast(_Float16, (unsigned short)(p0 >> 16));
                ah += v1 * __builtin_bit_cast(_Float16, (unsigned short)(p1 >> 16));
            }
            int4 ui = __builtin_bit_cast(int4, ah);
            int4 uo;
            uo.x = __shfl_xor(ui.x, 16);
            uo.y = __shfl_xor(ui.y, 16);
            uo.z = __shfl_xor(ui.z, 16);
            uo.w = __shfl_xor(ui.w, 16);
            ah += __builtin_bit_cast(half8v, uo);
            if (valid && l < 16) {
                float4 r0 = make_float4(fmaxf((float)ah[0], 0.f), fmaxf((float)ah[1], 0.f),
                                        fmaxf((float)ah[2], 0.f), fmaxf((float)ah[3], 0.f));
                float4 r1 = make_float4(fmaxf((float)ah[4], 0.f), fmaxf((float)ah[5], 0.f),
                                        fmaxf((float)ah[6], 0.f), fmaxf((float)ah[7], 0.f));
                *(float4*)(o + l16 * 8) = r0;
                *(float4*)(o + l16 * 8 + 4) = r1;
            }
        } else {
            // rare: process the two rows sequentially with the full wave
            for (int rr = 0; rr < 2; ++rr) {
                int rloc2 = iter * 8 + wavein * 2 + rr;
                int r2 = bkt * RPB2 + rloc2;
                if (r2 >= M_NODES) continue;
                int st2 = rloc2 ? hist[rloc2 - 1] : 0;
                int d2 = hist[rloc2] - st2;
                float* o2 = out + ((size_t)(dir ? M_NODES + r2 : r2)) * DCAT + c * DOUT;
                attend_row_wave(r2, st2, d2, ssrc, sdst, fbd, lcol, o2, lane);
            }
        }
    }
}

// ---------------- launch ----------------
extern "C" void kernel_launch(void* const* d_in, const int* in_sizes, int n_in,
                              void* d_out, int out_size, void* d_ws, size_t ws_size,
                              hipStream_t stream) {
    const float* u_prev  = (const float*)d_in[0];
    const float* i_prev  = (const float*)d_in[1];
    const float* w_user  = (const float*)d_in[2];
    const float* w_item  = (const float*)d_in[3];
    const float* a_u_src = (const float*)d_in[4];
    const float* a_u_dst = (const float*)d_in[5];
    const float* a_i_src = (const float*)d_in[6];
    const float* a_i_dst = (const float*)d_in[7];
    const int* u2i_row = (const int*)d_in[8];
    const int* u2i_col = (const int*)d_in[9];
    const int* i2u_row = (const int*)d_in[10];
    const int* i2u_col = (const int*)d_in[11];
    float* out = (float*)d_out;

    char* ws = (char*)d_ws;
    size_t woff = 0;
    auto alloc = [&](size_t bytes) -> char* {
        char* p = ws + woff;
        woff += (bytes + 255) & ~(size_t)255;
        return p;
    };
    unsigned short* AbU   = (unsigned short*)alloc((size_t)MPAD * 256 * 2);
    unsigned short* AbI   = (unsigned short*)alloc((size_t)MPAD * 256 * 2);
    unsigned short* BTu   = (unsigned short*)alloc((size_t)512 * 256 * 2);
    unsigned short* BTi   = (unsigned short*)alloc((size_t)512 * 256 * 2);
    unsigned short* Bvec  = (unsigned short*)alloc((size_t)2 * 4 * 4 * 64 * 8 * 2);
    unsigned short* fbu   = (unsigned short*)alloc((size_t)NC * M_NODES * DOUT * 2);
    unsigned short* fbi   = (unsigned short*)alloc((size_t)NC * M_NODES * DOUT * 2);
    float* su_src = (float*)alloc((size_t)NC * M_NODES * NH * 4);
    float* su_dst = (float*)alloc((size_t)NC * M_NODES * NH * 4);
    float* si_src = (float*)alloc((size_t)NC * M_NODES * NH * 4);
    float* si_dst = (float*)alloc((size_t)NC * M_NODES * NH * 4);
    int* cnt3     = (int*)alloc((size_t)8 * NBKT2 * NBLK * 4);
    int* btot     = (int*)alloc((size_t)8 * NBKT2 * 4);
    int* bbase    = (int*)alloc((size_t)8 * NBKT2 * 4);
    unsigned int* pairbuf = (unsigned int*)alloc((size_t)8 * NE * 4);

    k_prep<<<6392, 256, 0, stream>>>(u_prev, i_prev, w_user, w_item,
                                     a_u_src, a_u_dst, a_i_src, a_i_dst,
                                     u2i_row, i2u_row,
                                     AbU, AbI, BTu, BTi, Bvec, cnt3);
    k_gmm<<<1264, 256, 0, stream>>>(AbU, AbI, BTu, BTi, Bvec, fbu, fbi,
                                    su_src, su_dst, si_src, si_dst,
                                    cnt3, btot, bbase);
    k_bfill<<<1256, 256, 0, stream>>>(u2i_row, u2i_col, i2u_row, i2u_col,
                                      cnt3, bbase, pairbuf);
    k_fat<<<NBKT2 * 8, 256, 0, stream>>>(pairbuf, bbase, btot, fbu, fbi,
                                         su_src, su_dst, si_src, si_dst, out);
}

// Round 15
// 145.862 us; speedup vs baseline: 1.1995x; 1.1995x over previous
//
#include <hip/hip_runtime.h>
#include <math.h>

#define M_NODES 20000
#define MPAD    20096
#define NE      320000
#define NC      4
#define NH      4
#define DIN     256
#define DOUT    128
#define DCAT    512

// CSR bucket-build parameters (64-row buckets)
#define RPB2  64
#define NBKT2 313     // ceil(20000/64)
#define EPB   2048
#define NBLK  157
#define CAP2  4096

typedef __attribute__((ext_vector_type(8))) _Float16 half8v;
typedef __attribute__((ext_vector_type(2))) _Float16 half2v;
typedef __attribute__((ext_vector_type(4))) float f32x4;

__device__ __forceinline__ unsigned short f2h(float x) {
    _Float16 h = (_Float16)x;
    return __builtin_bit_cast(unsigned short, h);
}
__device__ __forceinline__ void gload16(const void* g, void* l) {
    __builtin_amdgcn_global_load_lds(
        (const __attribute__((address_space(1))) void*)g,
        (__attribute__((address_space(3))) void*)l,
        16, 0, 0);
}

// ---------------- fused prep: cvtA (u,i) | bcount | prepB | Bvec ----------------
__global__ __launch_bounds__(256) void k_prep(const float* __restrict__ u_prev, const float* __restrict__ i_prev,
                                              const float* __restrict__ w_user, const float* __restrict__ w_item,
                                              const float* __restrict__ a_u_src, const float* __restrict__ a_u_dst,
                                              const float* __restrict__ a_i_src, const float* __restrict__ a_i_dst,
                                              const int* __restrict__ u2i_row, const int* __restrict__ i2u_row,
                                              unsigned short* __restrict__ AbU, unsigned short* __restrict__ AbI,
                                              unsigned short* __restrict__ BTu, unsigned short* __restrict__ BTi,
                                              unsigned short* __restrict__ Bvec, int* __restrict__ cnt3) {
    __shared__ int hist[NBKT2];
    int bid = blockIdx.x, tid = threadIdx.x;
    if (bid < 5000) {
        int sideI = bid >= 2500;
        int t = (sideI ? bid - 2500 : bid) * 256 + tid;
        int row = t >> 5, kc = (t & 31) * 8;
        const float* src = sideI ? i_prev : u_prev;
        unsigned short* dst = sideI ? AbI : AbU;
        float4 x0 = *(const float4*)(src + (size_t)row * DIN + kc);
        float4 x1 = *(const float4*)(src + (size_t)row * DIN + kc + 4);
        float xs[8] = {x0.x, x0.y, x0.z, x0.w, x1.x, x1.y, x1.z, x1.w};
        unsigned int H[4];
#pragma unroll
        for (int p = 0; p < 4; ++p)
            H[p] = (unsigned int)f2h(xs[2 * p]) | ((unsigned int)f2h(xs[2 * p + 1]) << 16);
        *(uint4*)(dst + (size_t)row * 256 + kc) = make_uint4(H[0], H[1], H[2], H[3]);
        return;
    }
    if (bid < 6256) {
        // ---- bcount (int4-vectorized, 64-row buckets) ----
        int sub = bid - 5000;
        int combo = sub / NBLK, blk = sub % NBLK;
        int c = combo >> 1, dir = combo & 1;
        const int* rows = (dir ? i2u_row : u2i_row) + (size_t)c * NE;
        for (int i = tid; i < NBKT2; i += 256) hist[i] = 0;
        __syncthreads();
        int e0 = blk * EPB + tid * 8;
        if (e0 + 8 <= NE) {
            int4 r0 = *(const int4*)(rows + e0);
            int4 r1 = *(const int4*)(rows + e0 + 4);
            atomicAdd(&hist[r0.x >> 6], 1); atomicAdd(&hist[r0.y >> 6], 1);
            atomicAdd(&hist[r0.z >> 6], 1); atomicAdd(&hist[r0.w >> 6], 1);
            atomicAdd(&hist[r1.x >> 6], 1); atomicAdd(&hist[r1.y >> 6], 1);
            atomicAdd(&hist[r1.z >> 6], 1); atomicAdd(&hist[r1.w >> 6], 1);
        }
        __syncthreads();
        for (int i = tid; i < NBKT2; i += 256)
            cnt3[((size_t)combo * NBKT2 + i) * NBLK + blk] = hist[i];
        return;
    }
    if (bid < 6384) {
        int idx = (bid - 6256) * 256 + tid;
        int k = idx >> 7, j = idx & 127;
        float su = 0.f, si = 0.f;
        for (int c = 0; c < NC; ++c) {
            su += w_user[((size_t)c * DIN + k) * DOUT + j];
            si += w_item[((size_t)c * DIN + k) * DOUT + j];
            size_t n = (size_t)(c * DOUT + j) * 256;
            BTu[n + k] = f2h(su);
            BTi[n + k] = f2h(si);
        }
        return;
    }
    {
        // ---- Bvec ----
        int t = (bid - 6384) * 256 + tid;
        int lane = t & 63, ks = (t >> 6) & 3, c = (t >> 8) & 3, side = t >> 10;
        int col = lane & 15, g = lane >> 4;
        int kind = (col >> 2) & 1, h = col & 3;
        const float* araw = kind ? (side ? a_u_dst : a_i_dst) : (side ? a_i_src : a_u_src);
        unsigned int out2[4];
#pragma unroll
        for (int p = 0; p < 4; ++p) {
            unsigned short e2[2];
#pragma unroll
            for (int q = 0; q < 2; ++q) {
                int j = p * 2 + q;
                int kdim = ks * 32 + g * 8 + j;
                float s = 0.f;
                if (col < 8)
                    for (int c2 = 0; c2 <= c; ++c2) s += araw[(h * NC + c2) * DOUT + kdim];
                e2[q] = f2h(s);
            }
            out2[p] = (unsigned int)e2[0] | ((unsigned int)e2[1] << 16);
        }
        *(uint4*)(Bvec + ((size_t)(((side * 4 + c) * 4 + ks) * 64 + lane)) * 8) =
            make_uint4(out2[0], out2[1], out2[2], out2[3]);
    }
}

// ---- fused: MFMA GEMM K=256 fp16 + score epilogue (1256) | lvl1-scan (626) | lvl2-scan (8) ----
__global__ __launch_bounds__(256) void k_gmm(const unsigned short* __restrict__ AbU,
                                             const unsigned short* __restrict__ AbI,
                                             const unsigned short* __restrict__ BTu,
                                             const unsigned short* __restrict__ BTi,
                                             const unsigned short* __restrict__ Bvec,
                                             unsigned short* __restrict__ fbu,
                                             unsigned short* __restrict__ fbi,
                                             float* __restrict__ su_src, float* __restrict__ su_dst,
                                             float* __restrict__ si_src, float* __restrict__ si_dst,
                                             const int* __restrict__ cnt3, int* __restrict__ cpre,
                                             int* __restrict__ btot, int* __restrict__ bbase) {
    __shared__ unsigned short As[128 * 64];
    __shared__ unsigned short Bs[128 * 64];
    int bid = blockIdx.x, tid = threadIdx.x;
    if (bid < 1256) {
        int side = bid >= 628;
        int t = side ? bid - 628 : bid;
        int c = t / 157, mb = t % 157;
        const unsigned short* Ab = side ? AbI : AbU;
        const unsigned short* BT = side ? BTi : BTu;
        unsigned short* fb       = side ? fbi : fbu;
        int m0 = mb * 128;
        int w = tid >> 6, lane = tid & 63;
        int wrb = (w >> 1) * 64, wcb = (w & 1) * 64;
        int l15 = lane & 15, g = lane >> 4;
        int srow = lane >> 3;
        int scolSwz = (((lane & 7) ^ srow)) * 8;   // pre-swizzled source column (shorts)
        f32x4 acc[4][4] = {};
        for (int kt = 0; kt < 4; ++kt) {
            int k0 = kt * 64;
#pragma unroll
            for (int tt = 0; tt < 4; ++tt) {
                int chunk = w * 4 + tt;
                int row8 = chunk * 8 + srow;
                gload16(Ab + (size_t)(m0 + row8) * 256 + k0 + scolSwz, (char*)As + chunk * 1024);
                gload16(BT + (size_t)(c * 128 + row8) * 256 + k0 + scolSwz, (char*)Bs + chunk * 1024);
            }
            __syncthreads();
#pragma unroll
            for (int ks = 0; ks < 2; ++ks) {
                half8v a[4], b[4];
#pragma unroll
                for (int i = 0; i < 4; ++i) {
                    int row = wrb + i * 16 + l15;
                    int colSwz = (((ks * 4 + g) ^ (row & 7))) * 8;
                    a[i] = *(const half8v*)(&As[row * 64 + colSwz]);
                }
#pragma unroll
                for (int j = 0; j < 4; ++j) {
                    int row = wcb + j * 16 + l15;
                    int colSwz = (((ks * 4 + g) ^ (row & 7))) * 8;
                    b[j] = *(const half8v*)(&Bs[row * 64 + colSwz]);
                }
#pragma unroll
                for (int i = 0; i < 4; ++i)
#pragma unroll
                    for (int j = 0; j < 4; ++j)
                        acc[i][j] = __builtin_amdgcn_mfma_f32_16x16x32_f16(a[i], b[j], acc[i][j], 0, 0, 0);
            }
            __syncthreads();
        }
        // epilogue: write fb to global AND to swizzled LDS fp16 tile
#pragma unroll
        for (int i = 0; i < 4; ++i) {
#pragma unroll
            for (int r = 0; r < 4; ++r) {
                int nl = wrb + i * 16 + g * 4 + r;
                int node = m0 + nl;
                bool valid = node < M_NODES;
                int sw = (nl & 7) * 8;
#pragma unroll
                for (int j = 0; j < 4; ++j) {
                    int d = wcb + j * 16 + l15;
                    unsigned short hv = f2h(acc[i][j][r]);
                    if (valid) fb[((size_t)c * M_NODES + node) * DOUT + d] = hv;
                    if (d < 64) As[nl * 64 + (d ^ sw)] = hv;
                    else        Bs[nl * 64 + ((d - 64) ^ sw)] = hv;
                }
            }
        }
        __syncthreads();
        // scores (swizzled reads)
        {
            half8v bv[4];
#pragma unroll
            for (int ks = 0; ks < 4; ++ks)
                bv[ks] = *(const half8v*)(Bvec + ((size_t)(((side * 4 + c) * 4 + ks) * 64 + lane)) * 8);
#pragma unroll
            for (int mt2 = 0; mt2 < 2; ++mt2) {
                int mt = w * 2 + mt2;
                f32x4 sacc = {};
#pragma unroll
                for (int ks = 0; ks < 4; ++ks) {
                    int nl = mt * 16 + l15;
                    const unsigned short* base = (ks < 2) ? As : Bs;
                    int col = (ks & 1) * 32 + g * 8;
                    int colSwz = col ^ ((nl & 7) * 8);
                    half8v a = *(const half8v*)(&base[nl * 64 + colSwz]);
                    sacc = __builtin_amdgcn_mfma_f32_16x16x32_f16(a, bv[ks], sacc, 0, 0, 0);
                }
                int col = l15;
                if (col < 8) {
                    int kind = col >> 2, h = col & 3;
                    float* dst = kind ? (side ? si_dst : su_dst) : (side ? si_src : su_src);
#pragma unroll
                    for (int r = 0; r < 4; ++r) {
                        int node = m0 + mt * 16 + g * 4 + r;
                        if (node < M_NODES)
                            dst[((size_t)c * M_NODES + node) * 4 + h] = sacc[r];
                    }
                }
            }
        }
        return;
    }
    if (bid < 1882) {
        // ---- level-1: one wave per (combo,bucket): exclusive scan of 157 block counts ----
        int w = tid >> 6, lane = tid & 63;
        int wid = (bid - 1256) * 4 + w;              // < 2504
        int combo = wid & 7, bkt = wid >> 3;         // bkt < 313
        size_t base = ((size_t)combo * NBKT2 + bkt) * NBLK;
        int carry = 0;
#pragma unroll
        for (int ch = 0; ch < 3; ++ch) {
            int idx = ch * 64 + lane;
            int v = (idx < NBLK) ? cnt3[base + idx] : 0;
            int inc = v;
            for (int o = 1; o < 64; o <<= 1) {
                int tv = __shfl_up(inc, o);
                if (lane >= o) inc += tv;
            }
            if (idx < NBLK) cpre[base + idx] = carry + inc - v;
            carry += __shfl(inc, 63);
        }
        return;
    }
    {
        // ---- level-2: per combo: bucket totals (parallel sums) + 313-scan -> btot, bbase ----
        int combo = bid - 1882;
        int* tot = (int*)As;                         // alias: 313 ints << 16 KB
        for (int bkt = tid; bkt < NBKT2; bkt += 256) {
            size_t base = ((size_t)combo * NBKT2 + bkt) * NBLK;
            int s0 = 0, s1 = 0, s2 = 0, s3 = 0;
            int b = 0;
            for (; b + 4 <= NBLK; b += 4) {
                s0 += cnt3[base + b];
                s1 += cnt3[base + b + 1];
                s2 += cnt3[base + b + 2];
                s3 += cnt3[base + b + 3];
            }
            for (; b < NBLK; ++b) s0 += cnt3[base + b];
            int s = s0 + s1 + s2 + s3;
            tot[bkt] = s;
            btot[combo * NBKT2 + bkt] = s;
        }
        __syncthreads();
        if (tid < 64) {
            int carry = 0;
            for (int ch = 0; ch < 5; ++ch) {
                int idx = ch * 64 + tid;
                int v = (idx < NBKT2) ? tot[idx] : 0;
                int inc = v;
                for (int o = 1; o < 64; o <<= 1) {
                    int tv = __shfl_up(inc, o);
                    if (tid >= o) inc += tv;
                }
                if (idx < NBKT2) bbase[combo * NBKT2 + idx] = carry + inc - v;
                carry += __shfl(inc, 63);
            }
        }
    }
}

// ---------------- bfill (int4-vectorized), 1-D grid 1256 ----------------
__global__ __launch_bounds__(256) void k_bfill(const int* __restrict__ u2i_row, const int* __restrict__ u2i_col,
                                               const int* __restrict__ i2u_row, const int* __restrict__ i2u_col,
                                               const int* __restrict__ cpre, const int* __restrict__ bbase,
                                               unsigned int* __restrict__ pairbuf) {
    __shared__ int cur[NBKT2];
    int bid = blockIdx.x, tid = threadIdx.x;
    int combo = bid / NBLK, blk = bid % NBLK;
    int c = combo >> 1, dir = combo & 1;
    const int* rows = (dir ? i2u_row : u2i_row) + (size_t)c * NE;
    const int* cols = (dir ? i2u_col : u2i_col) + (size_t)c * NE;
    for (int i = tid; i < NBKT2; i += 256)
        cur[i] = bbase[combo * NBKT2 + i] + cpre[((size_t)combo * NBKT2 + i) * NBLK + blk];
    __syncthreads();
    unsigned int* pb = pairbuf + (size_t)combo * NE;
    int e0 = blk * EPB + tid * 8;
    if (e0 + 8 <= NE) {
        int4 r0 = *(const int4*)(rows + e0);
        int4 r1 = *(const int4*)(rows + e0 + 4);
        int4 c0 = *(const int4*)(cols + e0);
        int4 c1 = *(const int4*)(cols + e0 + 4);
        int rr[8] = {r0.x, r0.y, r0.z, r0.w, r1.x, r1.y, r1.z, r1.w};
        int cc[8] = {c0.x, c0.y, c0.z, c0.w, c1.x, c1.y, c1.z, c1.w};
#pragma unroll
        for (int k = 0; k < 8; ++k) {
            int pos = atomicAdd(&cur[rr[k] >> 6], 1);
            pb[pos] = ((unsigned int)rr[k] << 16) | (unsigned int)cc[k];
        }
    }
}

// ---------------- full-wave fallback for one row (cols from LDS) ----------------
__device__ void attend_row_wave(int r, int s0, int deg, const float* __restrict__ ssrc,
                                const float* __restrict__ sdst, const unsigned short* __restrict__ fbd,
                                const int* co, float* __restrict__ o, int lane) {
    if (deg <= 64) {
        float w = 0.f;
        int cl = 0;
        if (deg > 0) {
            float4 ssv = *(const float4*)(ssrc + (size_t)r * 4);
            float ss[4] = {ssv.x, ssv.y, ssv.z, ssv.w};
            float lg[4];
            if (lane < deg) {
                cl = co[s0 + lane];
                float4 sdv = *(const float4*)(sdst + (size_t)cl * 4);
                float sd[4] = {sdv.x, sdv.y, sdv.z, sdv.w};
#pragma unroll
                for (int h = 0; h < 4; ++h) {
                    float x = ss[h] + sd[h];
                    lg[h] = x > 0.f ? x : 0.01f * x;
                }
            } else {
#pragma unroll
                for (int h = 0; h < 4; ++h) lg[h] = -1e30f;
            }
            float ex[4], den[4];
#pragma unroll
            for (int h = 0; h < 4; ++h) {
                ex[h] = __expf(fminf(lg[h], 80.f));
                den[h] = ex[h];
            }
#pragma unroll
            for (int h = 0; h < 4; ++h)
                for (int o2 = 32; o2; o2 >>= 1) den[h] += __shfl_xor(den[h], o2);
#pragma unroll
            for (int h = 0; h < 4; ++h) w += ex[h] * (1.f / den[h]);
        }
        int q = lane >> 4, l16 = lane & 15;
        const unsigned short* fbl = fbd + l16 * 8;
        float a8[8] = {};
        for (int j = 0; j < deg; j += 4) {
            int e = j + q;
            float we = __shfl(w, e & 63);
            int   ce = __shfl(cl, e & 63);
            if (e < deg) {
                half8v v = *(const half8v*)(fbl + (size_t)ce * DOUT);
#pragma unroll
                for (int k = 0; k < 8; ++k) a8[k] = fmaf(we, (float)v[k], a8[k]);
            }
        }
#pragma unroll
        for (int i = 0; i < 8; ++i) {
            a8[i] += __shfl_xor(a8[i], 16);
            a8[i] += __shfl_xor(a8[i], 32);
        }
        if (lane < 16) {
            float4 r0 = make_float4(fmaxf(a8[0], 0.f), fmaxf(a8[1], 0.f), fmaxf(a8[2], 0.f), fmaxf(a8[3], 0.f));
            float4 r1 = make_float4(fmaxf(a8[4], 0.f), fmaxf(a8[5], 0.f), fmaxf(a8[6], 0.f), fmaxf(a8[7], 0.f));
            *(float4*)(o + l16 * 8) = r0;
            *(float4*)(o + l16 * 8 + 4) = r1;
        }
        return;
    }
    // slow path (deg > 64)
    float acc0 = 0.f, acc1 = 0.f;
    {
        float4 ssv = *(const float4*)(ssrc + (size_t)r * 4);
        float ss[4] = {ssv.x, ssv.y, ssv.z, ssv.w};
        float den[4] = {0.f, 0.f, 0.f, 0.f};
        for (int base = 0; base < deg; base += 64) {
            int e = base + lane;
            float ex[4] = {0.f, 0.f, 0.f, 0.f};
            if (e < deg) {
                int cl = co[s0 + e];
                float4 sdv = *(const float4*)(sdst + (size_t)cl * 4);
                float sd[4] = {sdv.x, sdv.y, sdv.z, sdv.w};
#pragma unroll
                for (int h = 0; h < 4; ++h) {
                    float x = ss[h] + sd[h];
                    x = x > 0.f ? x : 0.01f * x;
                    ex[h] = __expf(fminf(x, 80.f));
                }
            }
#pragma unroll
            for (int h = 0; h < 4; ++h) {
                float v = ex[h];
                for (int o2 = 32; o2; o2 >>= 1) v += __shfl_xor(v, o2);
                den[h] += v;
            }
        }
        float inv[4];
#pragma unroll
        for (int h = 0; h < 4; ++h) inv[h] = 1.f / den[h];
        for (int base = 0; base < deg; base += 64) {
            int e = base + lane;
            float w = 0.f;
            int cl = 0;
            if (e < deg) {
                cl = co[s0 + e];
                float4 sdv = *(const float4*)(sdst + (size_t)cl * 4);
                float sd[4] = {sdv.x, sdv.y, sdv.z, sdv.w};
#pragma unroll
                for (int h = 0; h < 4; ++h) {
                    float x = ss[h] + sd[h];
                    x = x > 0.f ? x : 0.01f * x;
                    w += __expf(fminf(x, 80.f)) * inv[h];
                }
            }
            int cnt2 = min(64, deg - base);
            for (int j = 0; j < cnt2; ++j) {
                float wj = __shfl(w, j);
                int   cj = __shfl(cl, j);
                half2v hv = *(const half2v*)(fbd + (size_t)cj * DOUT + lane * 2);
                acc0 = fmaf(wj, (float)hv[0], acc0);
                acc1 = fmaf(wj, (float)hv[1], acc1);
            }
        }
    }
    o[lane * 2]     = fmaxf(acc0, 0.f);
    o[lane * 2 + 1] = fmaxf(acc1, 0.f);
}

// ---------------- fused finalize+attend: 64-row buckets, grid 313*8 ----------------
__global__ __launch_bounds__(256) void k_fat(const unsigned int* __restrict__ pairbuf,
                                             const int* __restrict__ bbase, const int* __restrict__ btot,
                                             const unsigned short* __restrict__ fbu,
                                             const unsigned short* __restrict__ fbi,
                                             const float* __restrict__ su_src, const float* __restrict__ su_dst,
                                             const float* __restrict__ si_src, const float* __restrict__ si_dst,
                                             float* __restrict__ out) {
    __shared__ int hist[RPB2];
    __shared__ int cur[RPB2];
    __shared__ int lcol[CAP2];
    int tid = threadIdx.x, bid = blockIdx.x;
    int combo = bid & 7, bkt = bid >> 3;
    int c = combo >> 1, dir = combo & 1;
    int base = bbase[combo * NBKT2 + bkt];
    int cntb = btot[combo * NBKT2 + bkt];
    const unsigned int* pb = pairbuf + (size_t)combo * NE + base;
    // phase 1: bucket CSR in LDS
    if (tid < RPB2) hist[tid] = 0;
    __syncthreads();
    for (int k = tid; k < cntb; k += 256)
        atomicAdd(&hist[(pb[k] >> 16) & (RPB2 - 1)], 1);
    __syncthreads();
    if (tid < 64) {
        int v = hist[tid];
        int inc = v;
        for (int o = 1; o < 64; o <<= 1) {
            int t = __shfl_up(inc, o);
            if (tid >= o) inc += t;
        }
        hist[tid] = inc;
        cur[tid] = inc - v;
    }
    __syncthreads();
    for (int k = tid; k < cntb; k += 256) {
        unsigned int p = pb[k];
        int rl  = (p >> 16) & (RPB2 - 1);
        int pos = atomicAdd(&cur[rl], 1);
        if (pos < CAP2) lcol[pos] = (int)(p & 0xffffu);
    }
    __syncthreads();
    // phase 2: attend 64 rows (8 iters x 8 rows: 4 waves x 2 half-rows)
    const float* ssrc = (dir ? si_src : su_src) + (size_t)c * M_NODES * NH;
    const float* sdst = (dir ? su_dst : si_dst) + (size_t)c * M_NODES * NH;
    const unsigned short* fbd = (dir ? fbu : fbi) + (size_t)c * M_NODES * DOUT;
    int wavein = tid >> 6, lane = tid & 63;
    int half = lane >> 5, l = lane & 31;
    for (int iter = 0; iter < 8; ++iter) {
        int rloc = iter * 8 + wavein * 2 + half;
        int r = bkt * RPB2 + rloc;
        int start = rloc ? hist[rloc - 1] : 0;
        int deg = hist[rloc] - start;
        int degmax = max(deg, __shfl_xor(deg, 32));
        bool valid = r < M_NODES;
        float* o = out + ((size_t)(dir ? M_NODES + r : r)) * DCAT + c * DOUT;
        if (degmax <= 32) {
            unsigned int pk = 0;
            if (deg > 0) {
                float w = 0.f;
                int cl = 0;
                float4 ssv = *(const float4*)(ssrc + (size_t)r * 4);
                float ss[4] = {ssv.x, ssv.y, ssv.z, ssv.w};
                float lg[4];
                if (l < deg) {
                    cl = lcol[start + l];
                    float4 sdv = *(const float4*)(sdst + (size_t)cl * 4);
                    float sd[4] = {sdv.x, sdv.y, sdv.z, sdv.w};
#pragma unroll
                    for (int h = 0; h < 4; ++h) {
                        float x = ss[h] + sd[h];
                        lg[h] = x > 0.f ? x : 0.01f * x;
                    }
                } else {
#pragma unroll
                    for (int h = 0; h < 4; ++h) lg[h] = -1e30f;
                }
                float ex[4], den[4];
#pragma unroll
                for (int h = 0; h < 4; ++h) {
                    ex[h] = __expf(fminf(lg[h], 80.f));
                    den[h] = ex[h];
                }
#pragma unroll
                for (int h = 0; h < 4; ++h)
                    for (int o2 = 16; o2; o2 >>= 1) den[h] += __shfl_xor(den[h], o2);
#pragma unroll
                for (int h = 0; h < 4; ++h) w += ex[h] * (1.f / den[h]);
                pk = ((unsigned int)f2h(w) << 16) | (unsigned int)(cl & 0xffff);
            }
            int q2 = (l >> 4), l16 = l & 15;
            const char* fc = (const char*)(fbd + l16 * 8);
            half8v ah = {};
            int hb = half * 32;
            int j = 0;
            for (; j + 8 <= deg; j += 8) {
                unsigned int p0 = __shfl(pk, hb + j + q2);
                unsigned int p1 = __shfl(pk, hb + j + 2 + q2);
                unsigned int p2 = __shfl(pk, hb + j + 4 + q2);
                unsigned int p3 = __shfl(pk, hb + j + 6 + q2);
                half8v v0 = *(const half8v*)(fc + ((size_t)(p0 & 0xffffu) << 8));
                half8v v1 = *(const half8v*)(fc + ((size_t)(p1 & 0xffffu) << 8));
                half8v v2 = *(const half8v*)(fc + ((size_t)(p2 & 0xffffu) << 8));
                half8v v3 = *(const half8v*)(fc + ((size_t)(p3 & 0xffffu) << 8));
                ah += v0 * __builtin_bit_cast(_Float16, (unsigned short)(p0 >> 16));
                ah += v1 * __builtin_bit_cast(_Float16, (unsigned short)(p1 >> 16));
                ah += v2 * __builtin_bit_cast(_Float16, (unsigned short)(p2 >> 16));
                ah += v3 * __builtin_bit_cast(_Float16, (unsigned short)(p3 >> 16));
            }
            for (; j < deg; j += 4) {
                int e0 = j + q2, e1 = j + 2 + q2;
                unsigned int p0 = __shfl(pk, hb + min(e0, 31));
                unsigned int p1 = __shfl(pk, hb + min(e1, 31));
                p0 = (e0 < deg) ? p0 : 0u;
                p1 = (e1 < deg) ? p1 : 0u;
                half8v v0 = *(const half8v*)(fc + ((size_t)(p0 & 0xffffu) << 8));
                half8v v1 = *(const half8v*)(fc + ((size_t)(p1 & 0xffffu) << 8));
                ah += v0 * __builtin_bit_cast(_Float16, (unsigned short)(p0 >> 16));
                ah += v1 * __builtin_bit_cast(_Float16, (unsigned short)(p1 >> 16));
            }
            int4 ui = __builtin_bit_cast(int4, ah);
            int4 uo;
            uo.x = __shfl_xor(ui.x, 16);
            uo.y = __shfl_xor(ui.y, 16);
            uo.z = __shfl_xor(ui.z, 16);
            uo.w = __shfl_xor(ui.w, 16);
            ah += __builtin_bit_cast(half8v, uo);
            if (valid && l < 16) {
                float4 r0 = make_float4(fmaxf((float)ah[0], 0.f), fmaxf((float)ah[1], 0.f),
                                        fmaxf((float)ah[2], 0.f), fmaxf((float)ah[3], 0.f));
                float4 r1 = make_float4(fmaxf((float)ah[4], 0.f), fmaxf((float)ah[5], 0.f),
                                        fmaxf((float)ah[6], 0.f), fmaxf((float)ah[7], 0.f));
                *(float4*)(o + l16 * 8) = r0;
                *(float4*)(o + l16 * 8 + 4) = r1;
            }
        } else {
            for (int rr = 0; rr < 2; ++rr) {
                int rloc2 = iter * 8 + wavein * 2 + rr;
                int r2 = bkt * RPB2 + rloc2;
                if (r2 >= M_NODES) continue;
                int st2 = rloc2 ? hist[rloc2 - 1] : 0;
                int d2 = hist[rloc2] - st2;
                float* o2 = out + ((size_t)(dir ? M_NODES + r2 : r2)) * DCAT + c * DOUT;
                attend_row_wave(r2, st2, d2, ssrc, sdst, fbd, lcol, o2, lane);
            }
        }
    }
}

// ---------------- launch ----------------
extern "C" void kernel_launch(void* const* d_in, const int* in_sizes, int n_in,
                              void* d_out, int out_size, void* d_ws, size_t ws_size,
                              hipStream_t stream) {
    const float* u_prev  = (const float*)d_in[0];
    const float* i_prev  = (const float*)d_in[1];
    const float* w_user  = (const float*)d_in[2];
    const float* w_item  = (const float*)d_in[3];
    const float* a_u_src = (const float*)d_in[4];
    const float* a_u_dst = (const float*)d_in[5];
    const float* a_i_src = (const float*)d_in[6];
    const float* a_i_dst = (const float*)d_in[7];
    const int* u2i_row = (const int*)d_in[8];
    const int* u2i_col = (const int*)d_in[9];
    const int* i2u_row = (const int*)d_in[10];
    const int* i2u_col = (const int*)d_in[11];
    float* out = (float*)d_out;

    char* ws = (char*)d_ws;
    size_t woff = 0;
    auto alloc = [&](size_t bytes) -> char* {
        char* p = ws + woff;
        woff += (bytes + 255) & ~(size_t)255;
        return p;
    };
    unsigned short* AbU   = (unsigned short*)alloc((size_t)MPAD * 256 * 2);
    unsigned short* AbI   = (unsigned short*)alloc((size_t)MPAD * 256 * 2);
    unsigned short* BTu   = (unsigned short*)alloc((size_t)512 * 256 * 2);
    unsigned short* BTi   = (unsigned short*)alloc((size_t)512 * 256 * 2);
    unsigned short* Bvec  = (unsigned short*)alloc((size_t)2 * 4 * 4 * 64 * 8 * 2);
    unsigned short* fbu   = (unsigned short*)alloc((size_t)NC * M_NODES * DOUT * 2);
    unsigned short* fbi   = (unsigned short*)alloc((size_t)NC * M_NODES * DOUT * 2);
    float* su_src = (float*)alloc((size_t)NC * M_NODES * NH * 4);
    float* su_dst = (float*)alloc((size_t)NC * M_NODES * NH * 4);
    float* si_src = (float*)alloc((size_t)NC * M_NODES * NH * 4);
    float* si_dst = (float*)alloc((size_t)NC * M_NODES * NH * 4);
    int* cnt3     = (int*)alloc((size_t)8 * NBKT2 * NBLK * 4);
    int* cpre     = (int*)alloc((size_t)8 * NBKT2 * NBLK * 4);
    int* btot     = (int*)alloc((size_t)8 * NBKT2 * 4);
    int* bbase    = (int*)alloc((size_t)8 * NBKT2 * 4);
    unsigned int* pairbuf = (unsigned int*)alloc((size_t)8 * NE * 4);

    k_prep<<<6392, 256, 0, stream>>>(u_prev, i_prev, w_user, w_item,
                                     a_u_src, a_u_dst, a_i_src, a_i_dst,
                                     u2i_row, i2u_row,
                                     AbU, AbI, BTu, BTi, Bvec, cnt3);
    k_gmm<<<1890, 256, 0, stream>>>(AbU, AbI, BTu, BTi, Bvec, fbu, fbi,
                                    su_src, su_dst, si_src, si_dst,
                                    cnt3, cpre, btot, bbase);
    k_bfill<<<1256, 256, 0, stream>>>(u2i_row, u2i_col, i2u_row, i2u_col,
                                      cpre, bbase, pairbuf);
    k_fat<<<NBKT2 * 8, 256, 0, stream>>>(pairbuf, bbase, btot, fbu, fbi,
                                         su_src, su_dst, si_src, si_dst, out);
}

// Round 16
// 134.213 us; speedup vs baseline: 1.3036x; 1.0868x over previous
//
#include <hip/hip_runtime.h>
#include <math.h>

#define M_NODES 20000
#define MPAD    20096
#define NE      320000
#define NC      4
#define NH      4
#define DIN     256
#define DOUT    128
#define DCAT    512

// CSR bucket-build parameters (256-row buckets)
#define RPB   256
#define NBKT  79
#define EPB   2048
#define NBLK  157
#define CAP   8192

typedef __attribute__((ext_vector_type(8))) _Float16 half8v;
typedef __attribute__((ext_vector_type(2))) _Float16 half2v;
typedef __attribute__((ext_vector_type(4))) float f32x4;

__device__ __forceinline__ unsigned short f2h(float x) {
    _Float16 h = (_Float16)x;
    return __builtin_bit_cast(unsigned short, h);
}
__device__ __forceinline__ void gload16(const void* g, void* l) {
    __builtin_amdgcn_global_load_lds(
        (const __attribute__((address_space(1))) void*)g,
        (__attribute__((address_space(3))) void*)l,
        16, 0, 0);
}

// ---------------- fused prep: cvtA (u,i) | bcount | prepB | Bvec ----------------
// grid.x: [0,2500) cvtA-u, [2500,5000) cvtA-i, [5000,6256) bcount, [6256,6384) prepB, [6384,6392) Bvec
__global__ __launch_bounds__(256) void k_prep(const float* __restrict__ u_prev, const float* __restrict__ i_prev,
                                              const float* __restrict__ w_user, const float* __restrict__ w_item,
                                              const float* __restrict__ a_u_src, const float* __restrict__ a_u_dst,
                                              const float* __restrict__ a_i_src, const float* __restrict__ a_i_dst,
                                              const int* __restrict__ u2i_row, const int* __restrict__ i2u_row,
                                              unsigned short* __restrict__ AbU, unsigned short* __restrict__ AbI,
                                              unsigned short* __restrict__ BTu, unsigned short* __restrict__ BTi,
                                              unsigned short* __restrict__ Bvec, int* __restrict__ cnt3) {
    __shared__ int hist[NBKT];
    int bid = blockIdx.x, tid = threadIdx.x;
    if (bid < 5000) {
        int sideI = bid >= 2500;
        int t = (sideI ? bid - 2500 : bid) * 256 + tid;
        int row = t >> 5, kc = (t & 31) * 8;
        const float* src = sideI ? i_prev : u_prev;
        unsigned short* dst = sideI ? AbI : AbU;
        float4 x0 = *(const float4*)(src + (size_t)row * DIN + kc);
        float4 x1 = *(const float4*)(src + (size_t)row * DIN + kc + 4);
        float xs[8] = {x0.x, x0.y, x0.z, x0.w, x1.x, x1.y, x1.z, x1.w};
        unsigned int H[4];
#pragma unroll
        for (int p = 0; p < 4; ++p)
            H[p] = (unsigned int)f2h(xs[2 * p]) | ((unsigned int)f2h(xs[2 * p + 1]) << 16);
        *(uint4*)(dst + (size_t)row * 256 + kc) = make_uint4(H[0], H[1], H[2], H[3]);
        return;
    }
    if (bid < 6256) {
        // ---- bcount (int4-vectorized, 256-row buckets) ----
        int sub = bid - 5000;
        int combo = sub / NBLK, blk = sub % NBLK;
        int c = combo >> 1, dir = combo & 1;
        const int* rows = (dir ? i2u_row : u2i_row) + (size_t)c * NE;
        if (tid < NBKT) hist[tid] = 0;
        __syncthreads();
        int e0 = blk * EPB + tid * 8;
        if (e0 + 8 <= NE) {
            int4 r0 = *(const int4*)(rows + e0);
            int4 r1 = *(const int4*)(rows + e0 + 4);
            atomicAdd(&hist[r0.x >> 8], 1); atomicAdd(&hist[r0.y >> 8], 1);
            atomicAdd(&hist[r0.z >> 8], 1); atomicAdd(&hist[r0.w >> 8], 1);
            atomicAdd(&hist[r1.x >> 8], 1); atomicAdd(&hist[r1.y >> 8], 1);
            atomicAdd(&hist[r1.z >> 8], 1); atomicAdd(&hist[r1.w >> 8], 1);
        }
        __syncthreads();
        if (tid < NBKT) cnt3[((size_t)combo * NBKT + tid) * NBLK + blk] = hist[tid];
        return;
    }
    if (bid < 6384) {
        // ---- prepB: cumsum + transpose -> BT [512(n)][256(k)] fp16 ----
        int idx = (bid - 6256) * 256 + tid;
        int k = idx >> 7, j = idx & 127;
        float su = 0.f, si = 0.f;
        for (int c = 0; c < NC; ++c) {
            su += w_user[((size_t)c * DIN + k) * DOUT + j];
            si += w_item[((size_t)c * DIN + k) * DOUT + j];
            size_t n = (size_t)(c * DOUT + j) * 256;
            BTu[n + k] = f2h(su);
            BTi[n + k] = f2h(si);
        }
        return;
    }
    {
        // ---- Bvec ----
        int t = (bid - 6384) * 256 + tid;
        int lane = t & 63, ks = (t >> 6) & 3, c = (t >> 8) & 3, side = t >> 10;
        int col = lane & 15, g = lane >> 4;
        int kind = (col >> 2) & 1, h = col & 3;
        const float* araw = kind ? (side ? a_u_dst : a_i_dst) : (side ? a_i_src : a_u_src);
        unsigned int out2[4];
#pragma unroll
        for (int p = 0; p < 4; ++p) {
            unsigned short e2[2];
#pragma unroll
            for (int q = 0; q < 2; ++q) {
                int j = p * 2 + q;
                int kdim = ks * 32 + g * 8 + j;
                float s = 0.f;
                if (col < 8)
                    for (int c2 = 0; c2 <= c; ++c2) s += araw[(h * NC + c2) * DOUT + kdim];
                e2[q] = f2h(s);
            }
            out2[p] = (unsigned int)e2[0] | ((unsigned int)e2[1] << 16);
        }
        *(uint4*)(Bvec + ((size_t)(((side * 4 + c) * 4 + ks) * 64 + lane)) * 8) =
            make_uint4(out2[0], out2[1], out2[2], out2[3]);
    }
}

// ---- fused: MFMA GEMM K=256 fp16 + score epilogue (1256) | lvl1-scan (158) | lvl2-scan (8) ----
__global__ __launch_bounds__(256) void k_gmm(const unsigned short* __restrict__ AbU,
                                             const unsigned short* __restrict__ AbI,
                                             const unsigned short* __restrict__ BTu,
                                             const unsigned short* __restrict__ BTi,
                                             const unsigned short* __restrict__ Bvec,
                                             unsigned short* __restrict__ fbu,
                                             unsigned short* __restrict__ fbi,
                                             float* __restrict__ su_src, float* __restrict__ su_dst,
                                             float* __restrict__ si_src, float* __restrict__ si_dst,
                                             const int* __restrict__ cnt3, int* __restrict__ cpre,
                                             int* __restrict__ btot, int* __restrict__ bbase) {
    __shared__ unsigned short As[128 * 64];
    __shared__ unsigned short Bs[128 * 64];
    int bid = blockIdx.x, tid = threadIdx.x;
    if (bid < 1256) {
        int side = bid >= 628;
        int t = side ? bid - 628 : bid;
        int c = t / 157, mb = t % 157;
        const unsigned short* Ab = side ? AbI : AbU;
        const unsigned short* BT = side ? BTi : BTu;
        unsigned short* fb       = side ? fbi : fbu;
        int m0 = mb * 128;
        int w = tid >> 6, lane = tid & 63;
        int wrb = (w >> 1) * 64, wcb = (w & 1) * 64;
        int l15 = lane & 15, g = lane >> 4;
        int srow = lane >> 3;
        int scolSwz = (((lane & 7) ^ srow)) * 8;     // pre-swizzled source column (shorts)
        f32x4 acc[4][4] = {};
        for (int kt = 0; kt < 4; ++kt) {
            int k0 = kt * 64;
#pragma unroll
            for (int tt = 0; tt < 4; ++tt) {
                int chunk = w * 4 + tt;
                int row8 = chunk * 8 + srow;
                gload16(Ab + (size_t)(m0 + row8) * 256 + k0 + scolSwz, (char*)As + chunk * 1024);
                gload16(BT + (size_t)(c * 128 + row8) * 256 + k0 + scolSwz, (char*)Bs + chunk * 1024);
            }
            __syncthreads();
#pragma unroll
            for (int ks = 0; ks < 2; ++ks) {
                half8v a[4], b[4];
#pragma unroll
                for (int i = 0; i < 4; ++i) {
                    int row = wrb + i * 16 + l15;
                    int colSwz = (((ks * 4 + g) ^ (row & 7))) * 8;
                    a[i] = *(const half8v*)(&As[row * 64 + colSwz]);
                }
#pragma unroll
                for (int j = 0; j < 4; ++j) {
                    int row = wcb + j * 16 + l15;
                    int colSwz = (((ks * 4 + g) ^ (row & 7))) * 8;
                    b[j] = *(const half8v*)(&Bs[row * 64 + colSwz]);
                }
#pragma unroll
                for (int i = 0; i < 4; ++i)
#pragma unroll
                    for (int j = 0; j < 4; ++j)
                        acc[i][j] = __builtin_amdgcn_mfma_f32_16x16x32_f16(a[i], b[j], acc[i][j], 0, 0, 0);
            }
            __syncthreads();
        }
        // epilogue: write fb to global AND to swizzled LDS fp16 tile
#pragma unroll
        for (int i = 0; i < 4; ++i) {
#pragma unroll
            for (int r = 0; r < 4; ++r) {
                int nl = wrb + i * 16 + g * 4 + r;
                int node = m0 + nl;
                bool valid = node < M_NODES;
                int sw = (nl & 7) * 8;
#pragma unroll
                for (int j = 0; j < 4; ++j) {
                    int d = wcb + j * 16 + l15;
                    unsigned short hv = f2h(acc[i][j][r]);
                    if (valid) fb[((size_t)c * M_NODES + node) * DOUT + d] = hv;
                    if (d < 64) As[nl * 64 + (d ^ sw)] = hv;
                    else        Bs[nl * 64 + ((d - 64) ^ sw)] = hv;
                }
            }
        }
        __syncthreads();
        // scores (swizzled reads)
        {
            half8v bv[4];
#pragma unroll
            for (int ks = 0; ks < 4; ++ks)
                bv[ks] = *(const half8v*)(Bvec + ((size_t)(((side * 4 + c) * 4 + ks) * 64 + lane)) * 8);
#pragma unroll
            for (int mt2 = 0; mt2 < 2; ++mt2) {
                int mt = w * 2 + mt2;
                f32x4 sacc = {};
#pragma unroll
                for (int ks = 0; ks < 4; ++ks) {
                    int nl = mt * 16 + l15;
                    const unsigned short* base = (ks < 2) ? As : Bs;
                    int col = (ks & 1) * 32 + g * 8;
                    int colSwz = col ^ ((nl & 7) * 8);
                    half8v a = *(const half8v*)(&base[nl * 64 + colSwz]);
                    sacc = __builtin_amdgcn_mfma_f32_16x16x32_f16(a, bv[ks], sacc, 0, 0, 0);
                }
                int col = l15;
                if (col < 8) {
                    int kind = col >> 2, h = col & 3;
                    float* dst = kind ? (side ? si_dst : su_dst) : (side ? si_src : su_src);
#pragma unroll
                    for (int r = 0; r < 4; ++r) {
                        int node = m0 + mt * 16 + g * 4 + r;
                        if (node < M_NODES)
                            dst[((size_t)c * M_NODES + node) * 4 + h] = sacc[r];
                    }
                }
            }
        }
        return;
    }
    if (bid < 1414) {
        // ---- level-1: one wave per (combo,bucket): exclusive scan of 157 block counts ----
        int w = tid >> 6, lane = tid & 63;
        int wid = (bid - 1256) * 4 + w;              // < 632 exactly
        int combo = wid & 7, bkt = wid >> 3;         // bkt < 79
        size_t base = ((size_t)combo * NBKT + bkt) * NBLK;
        int carry = 0;
#pragma unroll
        for (int ch = 0; ch < 3; ++ch) {
            int idx = ch * 64 + lane;
            int v = (idx < NBLK) ? cnt3[base + idx] : 0;
            int inc = v;
            for (int o = 1; o < 64; o <<= 1) {
                int tv = __shfl_up(inc, o);
                if (lane >= o) inc += tv;
            }
            if (idx < NBLK) cpre[base + idx] = carry + inc - v;
            carry += __shfl(inc, 63);
        }
        return;
    }
    {
        // ---- level-2: per combo: bucket totals + 79-scan -> btot, bbase ----
        int combo = bid - 1414;
        int* tot = (int*)As;
        for (int bkt = tid; bkt < NBKT; bkt += 256) {
            size_t base = ((size_t)combo * NBKT + bkt) * NBLK;
            int s0 = 0, s1 = 0, s2 = 0, s3 = 0;
            int b = 0;
            for (; b + 4 <= NBLK; b += 4) {
                s0 += cnt3[base + b];
                s1 += cnt3[base + b + 1];
                s2 += cnt3[base + b + 2];
                s3 += cnt3[base + b + 3];
            }
            for (; b < NBLK; ++b) s0 += cnt3[base + b];
            int s = s0 + s1 + s2 + s3;
            tot[bkt] = s;
            btot[combo * NBKT + bkt] = s;
        }
        __syncthreads();
        if (tid < 64) {
            int carry = 0;
            for (int ch = 0; ch < 2; ++ch) {
                int idx = ch * 64 + tid;
                int v = (idx < NBKT) ? tot[idx] : 0;
                int inc = v;
                for (int o = 1; o < 64; o <<= 1) {
                    int tv = __shfl_up(inc, o);
                    if (tid >= o) inc += tv;
                }
                if (idx < NBKT) bbase[combo * NBKT + idx] = carry + inc - v;
                carry += __shfl(inc, 63);
            }
        }
    }
}

// ---------------- bfill (int4-vectorized), 1-D grid 1256 ----------------
__global__ __launch_bounds__(256) void k_bfill(const int* __restrict__ u2i_row, const int* __restrict__ u2i_col,
                                               const int* __restrict__ i2u_row, const int* __restrict__ i2u_col,
                                               const int* __restrict__ cpre, const int* __restrict__ bbase,
                                               unsigned int* __restrict__ pairbuf) {
    __shared__ int cur[NBKT];
    int bid = blockIdx.x, tid = threadIdx.x;
    int combo = bid / NBLK, blk = bid % NBLK;
    int c = combo >> 1, dir = combo & 1;
    const int* rows = (dir ? i2u_row : u2i_row) + (size_t)c * NE;
    const int* cols = (dir ? i2u_col : u2i_col) + (size_t)c * NE;
    if (tid < NBKT)
        cur[tid] = bbase[combo * NBKT + tid] + cpre[((size_t)combo * NBKT + tid) * NBLK + blk];
    __syncthreads();
    unsigned int* pb = pairbuf + (size_t)combo * NE;
    int e0 = blk * EPB + tid * 8;
    if (e0 + 8 <= NE) {
        int4 r0 = *(const int4*)(rows + e0);
        int4 r1 = *(const int4*)(rows + e0 + 4);
        int4 c0 = *(const int4*)(cols + e0);
        int4 c1 = *(const int4*)(cols + e0 + 4);
        int rr[8] = {r0.x, r0.y, r0.z, r0.w, r1.x, r1.y, r1.z, r1.w};
        int cc[8] = {c0.x, c0.y, c0.z, c0.w, c1.x, c1.y, c1.z, c1.w};
#pragma unroll
        for (int k = 0; k < 8; ++k) {
            int pos = atomicAdd(&cur[rr[k] >> 8], 1);
            pb[pos] = ((unsigned int)rr[k] << 16) | (unsigned int)cc[k];
        }
    }
}

// ---------------- finalize: bucket CSR, cols scattered in LDS, coalesced dump ----------------
__global__ __launch_bounds__(256) void k_finalize(const unsigned int* __restrict__ pairbuf,
                                                  const int* __restrict__ bbase, const int* __restrict__ btot,
                                                  int* __restrict__ csroff, int* __restrict__ csrcol) {
    __shared__ int hist[RPB];
    __shared__ int cur[RPB];
    __shared__ int lcol[CAP];
    int tid = threadIdx.x, bkt = blockIdx.x, combo = blockIdx.y;
    int base = bbase[combo * NBKT + bkt];
    int cntb = btot[combo * NBKT + bkt];
    const unsigned int* pb = pairbuf + (size_t)combo * NE + base;
    int* ccol = csrcol + (size_t)combo * NE + base;
    hist[tid] = 0;
    __syncthreads();
    for (int k = tid; k < cntb; k += 256)
        atomicAdd(&hist[(pb[k] >> 16) & (RPB - 1)], 1);
    __syncthreads();
    for (int st = 1; st < RPB; st <<= 1) {
        int v = (tid >= st) ? hist[tid - st] : 0;
        __syncthreads();
        hist[tid] += v;
        __syncthreads();
    }
    int ex = (tid == 0) ? 0 : hist[tid - 1];
    cur[tid] = ex;
    int row = bkt * RPB + tid;
    if (row < M_NODES) csroff[combo * (M_NODES + 1) + row] = base + ex;
    if (bkt == NBKT - 1 && tid == 0) csroff[combo * (M_NODES + 1) + M_NODES] = NE;
    __syncthreads();
    for (int k = tid; k < cntb; k += 256) {
        unsigned int p = pb[k];
        int rl  = (p >> 16) & (RPB - 1);
        int col = (int)(p & 0xffffu);
        int pos = atomicAdd(&cur[rl], 1);
        if (pos < CAP) lcol[pos] = col; else ccol[pos] = col;
    }
    __syncthreads();
    int lim = min(cntb, CAP);
    for (int k = tid; k < lim; k += 256) ccol[k] = lcol[k];
}

// ---------------- full-wave fallback for one row ----------------
__device__ void attend_row_wave(int r, int s0, int deg, const float* __restrict__ ssrc,
                                const float* __restrict__ sdst, const unsigned short* __restrict__ fbd,
                                const int* __restrict__ co, float* __restrict__ o, int lane) {
    if (deg <= 64) {
        float w = 0.f;
        int cl = 0;
        if (deg > 0) {
            float4 ssv = *(const float4*)(ssrc + (size_t)r * 4);
            float ss[4] = {ssv.x, ssv.y, ssv.z, ssv.w};
            float lg[4];
            if (lane < deg) {
                cl = co[s0 + lane];
                float4 sdv = *(const float4*)(sdst + (size_t)cl * 4);
                float sd[4] = {sdv.x, sdv.y, sdv.z, sdv.w};
#pragma unroll
                for (int h = 0; h < 4; ++h) {
                    float x = ss[h] + sd[h];
                    lg[h] = x > 0.f ? x : 0.01f * x;
                }
            } else {
#pragma unroll
                for (int h = 0; h < 4; ++h) lg[h] = -1e30f;
            }
            float ex[4], den[4];
#pragma unroll
            for (int h = 0; h < 4; ++h) {
                ex[h] = __expf(fminf(lg[h], 80.f));
                den[h] = ex[h];
            }
#pragma unroll
            for (int h = 0; h < 4; ++h)
                for (int o2 = 32; o2; o2 >>= 1) den[h] += __shfl_xor(den[h], o2);
#pragma unroll
            for (int h = 0; h < 4; ++h) w += ex[h] * (1.f / den[h]);
        }
        int q = lane >> 4, l16 = lane & 15;
        const unsigned short* fbl = fbd + l16 * 8;
        float a8[8] = {};
        for (int j = 0; j < deg; j += 4) {
            int e = j + q;
            float we = __shfl(w, e & 63);
            int   ce = __shfl(cl, e & 63);
            if (e < deg) {
                half8v v = *(const half8v*)(fbl + (size_t)ce * DOUT);
#pragma unroll
                for (int k = 0; k < 8; ++k) a8[k] = fmaf(we, (float)v[k], a8[k]);
            }
        }
#pragma unroll
        for (int i = 0; i < 8; ++i) {
            a8[i] += __shfl_xor(a8[i], 16);
            a8[i] += __shfl_xor(a8[i], 32);
        }
        if (lane < 16) {
            float4 r0 = make_float4(fmaxf(a8[0], 0.f), fmaxf(a8[1], 0.f), fmaxf(a8[2], 0.f), fmaxf(a8[3], 0.f));
            float4 r1 = make_float4(fmaxf(a8[4], 0.f), fmaxf(a8[5], 0.f), fmaxf(a8[6], 0.f), fmaxf(a8[7], 0.f));
            *(float4*)(o + l16 * 8) = r0;
            *(float4*)(o + l16 * 8 + 4) = r1;
        }
        return;
    }
    // slow path (deg > 64)
    float acc0 = 0.f, acc1 = 0.f;
    {
        float4 ssv = *(const float4*)(ssrc + (size_t)r * 4);
        float ss[4] = {ssv.x, ssv.y, ssv.z, ssv.w};
        float den[4] = {0.f, 0.f, 0.f, 0.f};
        for (int base = 0; base < deg; base += 64) {
            int e = base + lane;
            float ex[4] = {0.f, 0.f, 0.f, 0.f};
            if (e < deg) {
                int cl = co[s0 + e];
                float4 sdv = *(const float4*)(sdst + (size_t)cl * 4);
                float sd[4] = {sdv.x, sdv.y, sdv.z, sdv.w};
#pragma unroll
                for (int h = 0; h < 4; ++h) {
                    float x = ss[h] + sd[h];
                    x = x > 0.f ? x : 0.01f * x;
                    ex[h] = __expf(fminf(x, 80.f));
                }
            }
#pragma unroll
            for (int h = 0; h < 4; ++h) {
                float v = ex[h];
                for (int o2 = 32; o2; o2 >>= 1) v += __shfl_xor(v, o2);
                den[h] += v;
            }
        }
        float inv[4];
#pragma unroll
        for (int h = 0; h < 4; ++h) inv[h] = 1.f / den[h];
        for (int base = 0; base < deg; base += 64) {
            int e = base + lane;
            float w = 0.f;
            int cl = 0;
            if (e < deg) {
                cl = co[s0 + e];
                float4 sdv = *(const float4*)(sdst + (size_t)cl * 4);
                float sd[4] = {sdv.x, sdv.y, sdv.z, sdv.w};
#pragma unroll
                for (int h = 0; h < 4; ++h) {
                    float x = ss[h] + sd[h];
                    x = x > 0.f ? x : 0.01f * x;
                    w += __expf(fminf(x, 80.f)) * inv[h];
                }
            }
            int cnt2 = min(64, deg - base);
            for (int j = 0; j < cnt2; ++j) {
                float wj = __shfl(w, j);
                int   cj = __shfl(cl, j);
                half2v hv = *(const half2v*)(fbd + (size_t)cj * DOUT + lane * 2);
                acc0 = fmaf(wj, (float)hv[0], acc0);
                acc1 = fmaf(wj, (float)hv[1], acc1);
            }
        }
    }
    o[lane * 2]     = fmaxf(acc0, 0.f);
    o[lane * 2 + 1] = fmaxf(acc1, 0.f);
}

// ---------------- attention: 2 rows per wave (32-lane halves), combo = bid&7 ----------------
__global__ __launch_bounds__(256) void k_attend(const unsigned short* __restrict__ fbu, const unsigned short* __restrict__ fbi,
                                                const float* __restrict__ su_src, const float* __restrict__ su_dst,
                                                const float* __restrict__ si_src, const float* __restrict__ si_dst,
                                                const int* __restrict__ off, const int* __restrict__ cols,
                                                float* __restrict__ out) {
    int bid = blockIdx.x;
    int combo = bid & 7, c = combo >> 1, dir = combo & 1;
    int wavein = threadIdx.x >> 6, lane = threadIdx.x & 63;
    int half = lane >> 5, l = lane & 31;
    int rbase = (bid >> 3) * 8 + wavein * 2;
    const float* ssrc = (dir ? si_src : su_src) + (size_t)c * M_NODES * NH;
    const float* sdst = (dir ? su_dst : si_dst) + (size_t)c * M_NODES * NH;
    const unsigned short* fbd = (dir ? fbu : fbi) + (size_t)c * M_NODES * DOUT;
    const int* co = cols + (size_t)combo * NE;
    const int* offc = off + combo * (M_NODES + 1);
    int r = rbase + half;
    int s0 = offc[r];
    int deg = offc[r + 1] - s0;
    int degmax = max(deg, __shfl_xor(deg, 32));
    float* o = out + ((size_t)(dir ? M_NODES + r : r)) * DCAT + c * DOUT;

    if (degmax <= 32) {
        // -------- half-path: each 32-lane half owns one row --------
        unsigned int pk = 0;       // packed (fp16(w) << 16) | node-index
        if (deg > 0) {
            float w = 0.f;
            int cl = 0;
            float4 ssv = *(const float4*)(ssrc + (size_t)r * 4);
            float ss[4] = {ssv.x, ssv.y, ssv.z, ssv.w};
            float lg[4];
            if (l < deg) {
                cl = co[s0 + l];
                float4 sdv = *(const float4*)(sdst + (size_t)cl * 4);
                float sd[4] = {sdv.x, sdv.y, sdv.z, sdv.w};
#pragma unroll
                for (int h = 0; h < 4; ++h) {
                    float x = ss[h] + sd[h];
                    lg[h] = x > 0.f ? x : 0.01f * x;
                }
            } else {
#pragma unroll
                for (int h = 0; h < 4; ++h) lg[h] = -1e30f;
            }
            float ex[4], den[4];
#pragma unroll
            for (int h = 0; h < 4; ++h) {
                ex[h] = __expf(fminf(lg[h], 80.f));
                den[h] = ex[h];
            }
#pragma unroll
            for (int h = 0; h < 4; ++h)
                for (int o2 = 16; o2; o2 >>= 1) den[h] += __shfl_xor(den[h], o2);
#pragma unroll
            for (int h = 0; h < 4; ++h) w += ex[h] * (1.f / den[h]);
            pk = ((unsigned int)f2h(w) << 16) | (unsigned int)(cl & 0xffff);
        }
        // aggregation: packed broadcast (1 shfl/edge), fp16 pk_fma accumulation
        int q2 = (l >> 4), l16 = l & 15;
        const char* fc = (const char*)(fbd + l16 * 8);
        half8v ah = {};
        int hb = half * 32;
        int j = 0;
        for (; j + 8 <= deg; j += 8) {
            unsigned int p0 = __shfl(pk, hb + j + q2);
            unsigned int p1 = __shfl(pk, hb + j + 2 + q2);
            unsigned int p2 = __shfl(pk, hb + j + 4 + q2);
            unsigned int p3 = __shfl(pk, hb + j + 6 + q2);
            half8v v0 = *(const half8v*)(fc + ((size_t)(p0 & 0xffffu) << 8));
            half8v v1 = *(const half8v*)(fc + ((size_t)(p1 & 0xffffu) << 8));
            half8v v2 = *(const half8v*)(fc + ((size_t)(p2 & 0xffffu) << 8));
            half8v v3 = *(const half8v*)(fc + ((size_t)(p3 & 0xffffu) << 8));
            ah += v0 * __builtin_bit_cast(_Float16, (unsigned short)(p0 >> 16));
            ah += v1 * __builtin_bit_cast(_Float16, (unsigned short)(p1 >> 16));
            ah += v2 * __builtin_bit_cast(_Float16, (unsigned short)(p2 >> 16));
            ah += v3 * __builtin_bit_cast(_Float16, (unsigned short)(p3 >> 16));
        }
        for (; j < deg; j += 4) {
            int e0 = j + q2, e1 = j + 2 + q2;
            unsigned int p0 = __shfl(pk, hb + min(e0, 31));
            unsigned int p1 = __shfl(pk, hb + min(e1, 31));
            p0 = (e0 < deg) ? p0 : 0u;
            p1 = (e1 < deg) ? p1 : 0u;
            half8v v0 = *(const half8v*)(fc + ((size_t)(p0 & 0xffffu) << 8));
            half8v v1 = *(const half8v*)(fc + ((size_t)(p1 & 0xffffu) << 8));
            ah += v0 * __builtin_bit_cast(_Float16, (unsigned short)(p0 >> 16));
            ah += v1 * __builtin_bit_cast(_Float16, (unsigned short)(p1 >> 16));
        }
        // cross-half reduce on packed fp16
        int4 ui = __builtin_bit_cast(int4, ah);
        int4 uo;
        uo.x = __shfl_xor(ui.x, 16);
        uo.y = __shfl_xor(ui.y, 16);
        uo.z = __shfl_xor(ui.z, 16);
        uo.w = __shfl_xor(ui.w, 16);
        ah += __builtin_bit_cast(half8v, uo);
        if (l < 16) {
            float4 r0 = make_float4(fmaxf((float)ah[0], 0.f), fmaxf((float)ah[1], 0.f),
                                    fmaxf((float)ah[2], 0.f), fmaxf((float)ah[3], 0.f));
            float4 r1 = make_float4(fmaxf((float)ah[4], 0.f), fmaxf((float)ah[5], 0.f),
                                    fmaxf((float)ah[6], 0.f), fmaxf((float)ah[7], 0.f));
            *(float4*)(o + l16 * 8) = r0;
            *(float4*)(o + l16 * 8 + 4) = r1;
        }
        return;
    }

    // -------- rare fallback: process the two rows sequentially with the full wave --------
    for (int rr = 0; rr < 2; ++rr) {
        int r2 = rbase + rr;
        int t0 = offc[r2];
        int d2 = offc[r2 + 1] - t0;
        float* o2 = out + ((size_t)(dir ? M_NODES + r2 : r2)) * DCAT + c * DOUT;
        attend_row_wave(r2, t0, d2, ssrc, sdst, fbd, co, o2, lane);
    }
}

// ---------------- launch ----------------
extern "C" void kernel_launch(void* const* d_in, const int* in_sizes, int n_in,
                              void* d_out, int out_size, void* d_ws, size_t ws_size,
                              hipStream_t stream) {
    const float* u_prev  = (const float*)d_in[0];
    const float* i_prev  = (const float*)d_in[1];
    const float* w_user  = (const float*)d_in[2];
    const float* w_item  = (const float*)d_in[3];
    const float* a_u_src = (const float*)d_in[4];
    const float* a_u_dst = (const float*)d_in[5];
    const float* a_i_src = (const float*)d_in[6];
    const float* a_i_dst = (const float*)d_in[7];
    const int* u2i_row = (const int*)d_in[8];
    const int* u2i_col = (const int*)d_in[9];
    const int* i2u_row = (const int*)d_in[10];
    const int* i2u_col = (const int*)d_in[11];
    float* out = (float*)d_out;

    char* ws = (char*)d_ws;
    size_t woff = 0;
    auto alloc = [&](size_t bytes) -> char* {
        char* p = ws + woff;
        woff += (bytes + 255) & ~(size_t)255;
        return p;
    };
    unsigned short* AbU   = (unsigned short*)alloc((size_t)MPAD * 256 * 2);
    unsigned short* AbI   = (unsigned short*)alloc((size_t)MPAD * 256 * 2);
    unsigned short* BTu   = (unsigned short*)alloc((size_t)512 * 256 * 2);
    unsigned short* BTi   = (unsigned short*)alloc((size_t)512 * 256 * 2);
    unsigned short* Bvec  = (unsigned short*)alloc((size_t)2 * 4 * 4 * 64 * 8 * 2);
    unsigned short* fbu   = (unsigned short*)alloc((size_t)NC * M_NODES * DOUT * 2);
    unsigned short* fbi   = (unsigned short*)alloc((size_t)NC * M_NODES * DOUT * 2);
    float* su_src = (float*)alloc((size_t)NC * M_NODES * NH * 4);
    float* su_dst = (float*)alloc((size_t)NC * M_NODES * NH * 4);
    float* si_src = (float*)alloc((size_t)NC * M_NODES * NH * 4);
    float* si_dst = (float*)alloc((size_t)NC * M_NODES * NH * 4);
    int* csroff   = (int*)alloc((size_t)8 * (M_NODES + 1) * 4);
    int* csrcol   = (int*)alloc((size_t)8 * NE * 4);
    int* cnt3     = (int*)alloc((size_t)8 * NBKT * NBLK * 4);
    int* cpre     = (int*)alloc((size_t)8 * NBKT * NBLK * 4);
    int* btot     = (int*)alloc((size_t)8 * NBKT * 4);
    int* bbase    = (int*)alloc((size_t)8 * NBKT * 4);
    unsigned int* pairbuf = (unsigned int*)alloc((size_t)8 * NE * 4);

    k_prep<<<6392, 256, 0, stream>>>(u_prev, i_prev, w_user, w_item,
                                     a_u_src, a_u_dst, a_i_src, a_i_dst,
                                     u2i_row, i2u_row,
                                     AbU, AbI, BTu, BTi, Bvec, cnt3);
    k_gmm<<<1422, 256, 0, stream>>>(AbU, AbI, BTu, BTi, Bvec, fbu, fbi,
                                    su_src, su_dst, si_src, si_dst,
                                    cnt3, cpre, btot, bbase);
    k_bfill<<<1256, 256, 0, stream>>>(u2i_row, u2i_col, i2u_row, i2u_col,
                                      cpre, bbase, pairbuf);
    k_finalize<<<dim3(NBKT, 8), 256, 0, stream>>>(pairbuf, bbase, btot, csroff, csrcol);
    k_attend<<<dim3(M_NODES * 8 / 8), 256, 0, stream>>>(fbu, fbi, su_src, su_dst,
                                                        si_src, si_dst, csroff, csrcol, out);
}